// Round 2
// baseline (562797.852 us; speedup 1.0000x reference)
//
#include <hip/hip_runtime.h>
#include <math.h>

// mLSTM scan, 8192 serial steps. Strategy: weights resident on-chip
// (wh_w f32 in VGPRs: 256 regs/thread; wmh_w bf16-packed in LDS: 32KB/CU),
// one persistent workgroup per CU (256 blocks x 256 threads), per-step
// cross-CU exchange of the 2048-vectors m and h through LLC with
// flag-per-CU dataflow sync (agent-scope atomics). x_gates/x_mul are
// folded into the per-step dots via the embedding row (no 256MB buffer).
// Final FC chain on block 0 only.
//
// R1 -> R2: plain <<<256,256>>> launch instead of hipLaunchCooperativeKernel
// (cooperative launch failed silently -> nothing enqueued -> out stayed 0).
// No grid.sync() is used; co-residency holds because grid == 256 == #CUs and
// each CU fits >= 1 block (57KB LDS, 256 thr), so all blocks are resident.

#define WS_H   0
#define WS_M   2048
#define WS_C   4096
#define WS_FH  6144
#define WS_FM  6400
#define WS_TOT 6656

#define AGENT __HIP_MEMORY_SCOPE_AGENT

__device__ __forceinline__ float sigm(float x) { return 1.f / (1.f + __expf(-x)); }

__device__ __forceinline__ float wred(float v) {
  v += __shfl_xor(v, 32, 64);
  v += __shfl_xor(v, 16, 64);
  v += __shfl_xor(v, 8, 64);
  v += __shfl_xor(v, 4, 64);
  v += __shfl_xor(v, 2, 64);
  v += __shfl_xor(v, 1, 64);
  return v;
}

__global__ __launch_bounds__(256, 1)
void mlstm_kernel(const int* __restrict__ tokens,
                  const float* __restrict__ embed_w,
                  const float* __restrict__ wx_w,  const float* __restrict__ wx_b,
                  const float* __restrict__ wh_w,  const float* __restrict__ wh_b,
                  const float* __restrict__ wmx_w, const float* __restrict__ wmx_b,
                  const float* __restrict__ wmh_w, const float* __restrict__ wmh_b,
                  const float* __restrict__ fc1_w, const float* __restrict__ fc1_b,
                  const float* __restrict__ fc2_w, const float* __restrict__ fc2_b,
                  const float* __restrict__ fc3_w, const float* __restrict__ fc3_b,
                  const float* __restrict__ fc4_w, const float* __restrict__ fc4_b,
                  float* __restrict__ out, float* __restrict__ ws)
{
  __shared__ unsigned wmh_pk[8][16][64];          // 32KB: wmh rows (8/CU), bf16x2 packed
  __shared__ float gate_lds[4][8];
  __shared__ __align__(16) float fcx[4096];       // block-0 FC scratch
  __shared__ __align__(16) float fy[2048];

  const int tid  = threadIdx.x;
  const int lane = tid & 63;
  const int wv   = tid >> 6;        // wave 0..3 == gate type i,f,g,o
  const int b    = blockIdx.x;      // CU id 0..255

  float* h_buf = ws + WS_H;
  float* m_buf = ws + WS_M;
  float* c_buf = ws + WS_C;
  unsigned* flags_h = (unsigned*)(ws + WS_FH);
  unsigned* flags_m = (unsigned*)(ws + WS_FM);

  // ---------------- preload weights ----------------
  // wave wv owns gate rows gr = 2048*wv + 8*b + s (s=0..7); lane holds k = lane+64j
  float whR[8][32];
  float wxR[8][2];
  float gBias[8];
  {
    const int gr0 = 2048 * wv + 8 * b;
#pragma unroll
    for (int s = 0; s < 8; ++s) {
      const float* row = wh_w + (size_t)(gr0 + s) * 2048;
#pragma unroll
      for (int j = 0; j < 32; ++j) whR[s][j] = row[lane + 64 * j];
      wxR[s][0] = wx_w[(size_t)(gr0 + s) * 128 + lane];
      wxR[s][1] = wx_w[(size_t)(gr0 + s) * 128 + lane + 64];
      gBias[s] = wh_b[gr0 + s] + wx_b[gr0 + s];
    }
  }
  // wave wv owns hidden units u = 2*wv+rr (local), gu = 8*b+u (global)
  float wmxR[2][2], vB[2], xB[2];
#pragma unroll
  for (int rr = 0; rr < 2; ++rr) {
    const int gu = 8 * b + 2 * wv + rr;
    wmxR[rr][0] = wmx_w[(size_t)gu * 128 + lane];
    wmxR[rr][1] = wmx_w[(size_t)gu * 128 + lane + 64];
    vB[rr] = wmh_b[gu];
    xB[rr] = wmx_b[gu];
  }
  // wmh rows -> LDS as packed bf16 pairs: lo = w[gu][l+128p] (=k at j=2p),
  // hi = w[gu][l+128p+64] (=k at j=2p+1). RNE rounding.
  for (int idx = tid; idx < 8 * 16 * 64; idx += 256) {
    int u = idx >> 10, p = (idx >> 6) & 15, l = idx & 63;
    float a = wmh_w[(size_t)(8 * b + u) * 2048 + l + 128 * p];
    float c = wmh_w[(size_t)(8 * b + u) * 2048 + l + 128 * p + 64];
    unsigned xa = __float_as_uint(a); xa = (xa + 0x7fffu + ((xa >> 16) & 1u)) >> 16;
    unsigned xc = __float_as_uint(c); xc = (xc + 0x7fffu + ((xc >> 16) & 1u)) >> 16;
    wmh_pk[u][p][l] = xa | (xc << 16);
  }
  __syncthreads();

  float creg = 0.f;
  int tok = tokens[0];
  float e0 = embed_w[tok * 128 + lane];
  float e1 = embed_w[tok * 128 + lane + 64];

  for (int t = 0; t < 8192; ++t) {
    // ---- phase 1: wait h (flags_h >= t; h_buf holds h_{t-1}, zeros at t=0) ----
    while (__hip_atomic_load(&flags_h[tid], __ATOMIC_RELAXED, AGENT) < (unsigned)t) {}
    __syncthreads();
    __threadfence();
    float hloc[32];
#pragma unroll
    for (int j = 0; j < 32; ++j)
      hloc[j] = __hip_atomic_load(&h_buf[lane + 64 * j], __ATOMIC_RELAXED, AGENT);
#pragma unroll
    for (int rr = 0; rr < 2; ++rr) {
      const int u = 2 * wv + rr;
      float acc = 0.f;
#pragma unroll
      for (int p = 0; p < 16; ++p) {
        unsigned pk = wmh_pk[u][p][lane];
        acc = fmaf(__uint_as_float(pk << 16),         hloc[2 * p],     acc);
        acc = fmaf(__uint_as_float(pk & 0xffff0000u), hloc[2 * p + 1], acc);
      }
      float ax = fmaf(wmxR[rr][0], e0, wmxR[rr][1] * e1);
      acc = wred(acc);
      ax  = wred(ax);
      if (lane == 0) {
        float m = (ax + xB[rr]) * (acc + vB[rr]);   // m = xm * (wmh@h + b)
        __hip_atomic_store(&m_buf[8 * b + u], m, __ATOMIC_RELAXED, AGENT);
      }
    }
    __syncthreads();          // drains each storer's vmcnt before barrier
    __threadfence();
    if (tid == 0)
      __hip_atomic_store(&flags_m[b], (unsigned)(t + 1), __ATOMIC_RELAXED, AGENT);

    // ---- phase 2: wait all m ----
    while (__hip_atomic_load(&flags_m[tid], __ATOMIC_RELAXED, AGENT) < (unsigned)(t + 1)) {}
    __syncthreads();
    __threadfence();
    float mloc[32];
#pragma unroll
    for (int j = 0; j < 32; ++j)
      mloc[j] = __hip_atomic_load(&m_buf[lane + 64 * j], __ATOMIC_RELAXED, AGENT);
    float ga[8];
#pragma unroll
    for (int s = 0; s < 8; ++s) {
      float acc = fmaf(wxR[s][0], e0, wxR[s][1] * e1);   // x_gates folded in
#pragma unroll
      for (int j = 0; j < 32; ++j) acc = fmaf(whR[s][j], mloc[j], acc);
      ga[s] = acc;
    }
    // prefetch next token + embedding (hides under reduce/exchange)
    if (t + 1 < 8192) {
      tok = tokens[t + 1];
      e0 = embed_w[tok * 128 + lane];
      e1 = embed_w[tok * 128 + lane + 64];
    }
#pragma unroll
    for (int s = 0; s < 8; ++s) {
      float r = wred(ga[s]);
      if (lane == 0) gate_lds[wv][s] = r + gBias[s];
    }
    __syncthreads();
    if (tid < 8) {
      float gi = gate_lds[0][tid], gf = gate_lds[1][tid];
      float gg = gate_lds[2][tid], go = gate_lds[3][tid];
      float c = sigm(gf) * creg + sigm(gi) * tanhf(gg);
      creg = c;
      float h = sigm(go) * tanhf(c);
      __hip_atomic_store(&h_buf[8 * b + tid], h, __ATOMIC_RELAXED, AGENT);
    }
    __syncthreads();
    __threadfence();
    if (tid == 0)
      __hip_atomic_store(&flags_h[b], (unsigned)(t + 1), __ATOMIC_RELAXED, AGENT);
  }

  // ---- publish c ----
  if (tid < 8)
    __hip_atomic_store(&c_buf[8 * b + tid], creg, __ATOMIC_RELAXED, AGENT);
  __syncthreads();
  __threadfence();
  if (tid == 0)
    __hip_atomic_store(&flags_m[b], 8193u, __ATOMIC_RELAXED, AGENT);

  if (b != 0) return;

  // ---- final FC chain on block 0 only (~10 MMAC, ~20us) ----
  while (__hip_atomic_load(&flags_m[tid], __ATOMIC_RELAXED, AGENT) < 8193u) {}
  __syncthreads();
  __threadfence();
  for (int i = tid; i < 2048; i += 256) {
    fcx[i]        = __hip_atomic_load(&h_buf[i], __ATOMIC_RELAXED, AGENT);
    fcx[2048 + i] = __hip_atomic_load(&c_buf[i], __ATOMIC_RELAXED, AGENT);
  }
  __syncthreads();
  // fc1: [2048 x 4096]
  for (int r = tid; r < 2048; r += 256) {
    const float4* wr = (const float4*)(fc1_w + (size_t)r * 4096);
    const float4* xv = (const float4*)fcx;
    float a0 = 0, a1 = 0, a2 = 0, a3 = 0;
    for (int k = 0; k < 1024; ++k) {
      float4 w = wr[k], x = xv[k];
      a0 = fmaf(w.x, x.x, a0); a1 = fmaf(w.y, x.y, a1);
      a2 = fmaf(w.z, x.z, a2); a3 = fmaf(w.w, x.w, a3);
    }
    fy[r] = fmaxf((a0 + a1) + (a2 + a3) + fc1_b[r], 0.f);
  }
  __syncthreads();
  // fc2: [512 x 2048] reads fy -> fcx[0..512)
  for (int r = tid; r < 512; r += 256) {
    const float4* wr = (const float4*)(fc2_w + (size_t)r * 2048);
    const float4* xv = (const float4*)fy;
    float a0 = 0, a1 = 0, a2 = 0, a3 = 0;
    for (int k = 0; k < 512; ++k) {
      float4 w = wr[k], x = xv[k];
      a0 = fmaf(w.x, x.x, a0); a1 = fmaf(w.y, x.y, a1);
      a2 = fmaf(w.z, x.z, a2); a3 = fmaf(w.w, x.w, a3);
    }
    fcx[r] = fmaxf((a0 + a1) + (a2 + a3) + fc2_b[r], 0.f);
  }
  __syncthreads();
  // fc3: [1024 x 512] reads fcx[0..512) -> fy[0..1024)
  for (int r = tid; r < 1024; r += 256) {
    const float4* wr = (const float4*)(fc3_w + (size_t)r * 512);
    const float4* xv = (const float4*)fcx;
    float a0 = 0, a1 = 0, a2 = 0, a3 = 0;
    for (int k = 0; k < 128; ++k) {
      float4 w = wr[k], x = xv[k];
      a0 = fmaf(w.x, x.x, a0); a1 = fmaf(w.y, x.y, a1);
      a2 = fmaf(w.z, x.z, a2); a3 = fmaf(w.w, x.w, a3);
    }
    fy[r] = fmaxf((a0 + a1) + (a2 + a3) + fc3_b[r], 0.f);
  }
  __syncthreads();
  // fc4: [5 x 1024]
  if (tid < 5) {
    const float4* wr = (const float4*)(fc4_w + (size_t)tid * 1024);
    const float4* xv = (const float4*)fy;
    float a0 = 0, a1 = 0, a2 = 0, a3 = 0;
    for (int k = 0; k < 256; ++k) {
      float4 w = wr[k], x = xv[k];
      a0 = fmaf(w.x, x.x, a0); a1 = fmaf(w.y, x.y, a1);
      a2 = fmaf(w.z, x.z, a2); a3 = fmaf(w.w, x.w, a3);
    }
    out[tid] = fmaxf((a0 + a1) + (a2 + a3) + fc4_b[tid], 0.f);
  }
}

extern "C" void kernel_launch(void* const* d_in, const int* in_sizes, int n_in,
                              void* d_out, int out_size, void* d_ws, size_t ws_size,
                              hipStream_t stream)
{
  const int*   tokens = (const int*)  d_in[0];
  const float* embed_w = (const float*)d_in[1];
  const float* wx_w   = (const float*)d_in[2];
  const float* wx_b   = (const float*)d_in[3];
  const float* wh_w   = (const float*)d_in[4];
  const float* wh_b   = (const float*)d_in[5];
  const float* wmx_w  = (const float*)d_in[6];
  const float* wmx_b  = (const float*)d_in[7];
  const float* wmh_w  = (const float*)d_in[8];
  const float* wmh_b  = (const float*)d_in[9];
  const float* fc1_w  = (const float*)d_in[10];
  const float* fc1_b  = (const float*)d_in[11];
  const float* fc2_w  = (const float*)d_in[12];
  const float* fc2_b  = (const float*)d_in[13];
  const float* fc3_w  = (const float*)d_in[14];
  const float* fc3_b  = (const float*)d_in[15];
  const float* fc4_w  = (const float*)d_in[16];
  const float* fc4_b  = (const float*)d_in[17];
  float* out = (float*)d_out;
  float* ws  = (float*)d_ws;

  // zero h_buf/m_buf/c_buf + flags every call (graph-replay safe)
  hipMemsetAsync(d_ws, 0, WS_TOT * sizeof(float), stream);

  // Plain launch: no grid.sync() anywhere; co-residency guaranteed by
  // grid == 256 == #CUs with >= 1 block/CU of resources.
  mlstm_kernel<<<dim3(256), dim3(256), 0, stream>>>(
      tokens, embed_w, wx_w, wx_b, wh_w, wh_b,
      wmx_w, wmx_b, wmh_w, wmh_b,
      fc1_w, fc1_b, fc2_w, fc2_b, fc3_w, fc3_b,
      fc4_w, fc4_b, out, ws);
}

// Round 3
// 112709.387 us; speedup vs baseline: 4.9934x; 4.9934x over previous
//
#include <hip/hip_runtime.h>
#include <math.h>

// mLSTM scan, 8192 serial steps. Strategy: weights resident on-chip
// (wh_w f32 in VGPRs/AGPRs: 256 regs/thread; wmh_w bf16-packed in LDS:
// 32KB/CU), one persistent workgroup per CU (256 blocks x 256 threads),
// per-step cross-CU exchange of the 2048-vectors m and h through LLC with
// flag-per-CU dataflow sync (agent-scope relaxed atomics, sc1 = LLC
// coherent point). x_gates/x_mul folded into per-step dots via the
// embedding row. Final FC chain on block 0 only.
//
// R2 -> R3: removed ALL __threadfence() (agent fence = buffer_wbl2+buffer_inv
// L2 maintenance ops; 6/step/CU serialized at per-XCD L2 ~= the observed
// 34us/phase). Ordering now: sc1 write-through data stores + vmcnt drain
// (implicit in __syncthreads, explicit asm before flag stores) -> flag store;
// consumer sc1 loads bypass L1/L2 so no invalidate is needed.

#define WS_H   0
#define WS_M   2048
#define WS_C   4096
#define WS_FH  6144
#define WS_FM  6400
#define WS_TOT 6656

#define AGENT __HIP_MEMORY_SCOPE_AGENT

__device__ __forceinline__ void drain_vmem() {
  asm volatile("s_waitcnt vmcnt(0)" ::: "memory");
}

__device__ __forceinline__ float sigm(float x) { return 1.f / (1.f + __expf(-x)); }

__device__ __forceinline__ float wred(float v) {
  v += __shfl_xor(v, 32, 64);
  v += __shfl_xor(v, 16, 64);
  v += __shfl_xor(v, 8, 64);
  v += __shfl_xor(v, 4, 64);
  v += __shfl_xor(v, 2, 64);
  v += __shfl_xor(v, 1, 64);
  return v;
}

__global__ __launch_bounds__(256, 1)
void mlstm_kernel(const int* __restrict__ tokens,
                  const float* __restrict__ embed_w,
                  const float* __restrict__ wx_w,  const float* __restrict__ wx_b,
                  const float* __restrict__ wh_w,  const float* __restrict__ wh_b,
                  const float* __restrict__ wmx_w, const float* __restrict__ wmx_b,
                  const float* __restrict__ wmh_w, const float* __restrict__ wmh_b,
                  const float* __restrict__ fc1_w, const float* __restrict__ fc1_b,
                  const float* __restrict__ fc2_w, const float* __restrict__ fc2_b,
                  const float* __restrict__ fc3_w, const float* __restrict__ fc3_b,
                  const float* __restrict__ fc4_w, const float* __restrict__ fc4_b,
                  float* __restrict__ out, float* __restrict__ ws)
{
  __shared__ unsigned wmh_pk[8][16][64];          // 32KB: wmh rows (8/CU), bf16x2 packed
  __shared__ float gate_lds[4][8];
  __shared__ __align__(16) float fcx[4096];       // block-0 FC scratch
  __shared__ __align__(16) float fy[2048];

  const int tid  = threadIdx.x;
  const int lane = tid & 63;
  const int wv   = tid >> 6;        // wave 0..3 == gate type i,f,g,o
  const int b    = blockIdx.x;      // CU id 0..255

  float* h_buf = ws + WS_H;
  float* m_buf = ws + WS_M;
  float* c_buf = ws + WS_C;
  unsigned* flags_h = (unsigned*)(ws + WS_FH);
  unsigned* flags_m = (unsigned*)(ws + WS_FM);

  // ---------------- preload weights ----------------
  // wave wv owns gate rows gr = 2048*wv + 8*b + s (s=0..7); lane holds k = lane+64j
  float whR[8][32];
  float wxR[8][2];
  float gBias[8];
  {
    const int gr0 = 2048 * wv + 8 * b;
#pragma unroll
    for (int s = 0; s < 8; ++s) {
      const float* row = wh_w + (size_t)(gr0 + s) * 2048;
#pragma unroll
      for (int j = 0; j < 32; ++j) whR[s][j] = row[lane + 64 * j];
      wxR[s][0] = wx_w[(size_t)(gr0 + s) * 128 + lane];
      wxR[s][1] = wx_w[(size_t)(gr0 + s) * 128 + lane + 64];
      gBias[s] = wh_b[gr0 + s] + wx_b[gr0 + s];
    }
  }
  // wave wv owns hidden units u = 2*wv+rr (local), gu = 8*b+u (global)
  float wmxR[2][2], vB[2], xB[2];
#pragma unroll
  for (int rr = 0; rr < 2; ++rr) {
    const int gu = 8 * b + 2 * wv + rr;
    wmxR[rr][0] = wmx_w[(size_t)gu * 128 + lane];
    wmxR[rr][1] = wmx_w[(size_t)gu * 128 + lane + 64];
    vB[rr] = wmh_b[gu];
    xB[rr] = wmx_b[gu];
  }
  // wmh rows -> LDS as packed bf16 pairs: lo = w[gu][l+128p] (=k at j=2p),
  // hi = w[gu][l+128p+64] (=k at j=2p+1). RNE rounding.
  for (int idx = tid; idx < 8 * 16 * 64; idx += 256) {
    int u = idx >> 10, p = (idx >> 6) & 15, l = idx & 63;
    float a = wmh_w[(size_t)(8 * b + u) * 2048 + l + 128 * p];
    float c = wmh_w[(size_t)(8 * b + u) * 2048 + l + 128 * p + 64];
    unsigned xa = __float_as_uint(a); xa = (xa + 0x7fffu + ((xa >> 16) & 1u)) >> 16;
    unsigned xc = __float_as_uint(c); xc = (xc + 0x7fffu + ((xc >> 16) & 1u)) >> 16;
    wmh_pk[u][p][l] = xa | (xc << 16);
  }
  __syncthreads();

  float creg = 0.f;
  int tok = tokens[0];
  float e0 = embed_w[tok * 128 + lane];
  float e1 = embed_w[tok * 128 + lane + 64];

  for (int t = 0; t < 8192; ++t) {
    // ---- phase 1: wait h (flags_h >= t; h_buf holds h_{t-1}, zeros at t=0) ----
    while (__hip_atomic_load(&flags_h[tid], __ATOMIC_RELAXED, AGENT) < (unsigned)t) {}
    __syncthreads();
    float hloc[32];
#pragma unroll
    for (int j = 0; j < 32; ++j)
      hloc[j] = __hip_atomic_load(&h_buf[lane + 64 * j], __ATOMIC_RELAXED, AGENT);
#pragma unroll
    for (int rr = 0; rr < 2; ++rr) {
      const int u = 2 * wv + rr;
      float acc = 0.f;
#pragma unroll
      for (int p = 0; p < 16; ++p) {
        unsigned pk = wmh_pk[u][p][lane];
        acc = fmaf(__uint_as_float(pk << 16),         hloc[2 * p],     acc);
        acc = fmaf(__uint_as_float(pk & 0xffff0000u), hloc[2 * p + 1], acc);
      }
      float ax = fmaf(wmxR[rr][0], e0, wmxR[rr][1] * e1);
      acc = wred(acc);
      ax  = wred(ax);
      if (lane == 0) {
        float m = (ax + xB[rr]) * (acc + vB[rr]);   // m = xm * (wmh@h + b)
        __hip_atomic_store(&m_buf[8 * b + u], m, __ATOMIC_RELAXED, AGENT);
      }
    }
    __syncthreads();          // compiler drains vmcnt before s_barrier
    if (tid == 0) {
      drain_vmem();           // belt & braces: own-wave stores at LLC
      __hip_atomic_store(&flags_m[b], (unsigned)(t + 1), __ATOMIC_RELAXED, AGENT);
    }

    // ---- phase 2: wait all m ----
    while (__hip_atomic_load(&flags_m[tid], __ATOMIC_RELAXED, AGENT) < (unsigned)(t + 1)) {}
    __syncthreads();
    float mloc[32];
#pragma unroll
    for (int j = 0; j < 32; ++j)
      mloc[j] = __hip_atomic_load(&m_buf[lane + 64 * j], __ATOMIC_RELAXED, AGENT);
    float ga[8];
#pragma unroll
    for (int s = 0; s < 8; ++s) {
      float acc = fmaf(wxR[s][0], e0, wxR[s][1] * e1);   // x_gates folded in
#pragma unroll
      for (int j = 0; j < 32; ++j) acc = fmaf(whR[s][j], mloc[j], acc);
      ga[s] = acc;
    }
    // prefetch next token + embedding (hides under reduce/exchange)
    if (t + 1 < 8192) {
      tok = tokens[t + 1];
      e0 = embed_w[tok * 128 + lane];
      e1 = embed_w[tok * 128 + lane + 64];
    }
#pragma unroll
    for (int s = 0; s < 8; ++s) {
      float r = wred(ga[s]);
      if (lane == 0) gate_lds[wv][s] = r + gBias[s];
    }
    __syncthreads();
    if (tid < 8) {
      float gi = gate_lds[0][tid], gf = gate_lds[1][tid];
      float gg = gate_lds[2][tid], go = gate_lds[3][tid];
      float c = sigm(gf) * creg + sigm(gi) * tanhf(gg);
      creg = c;
      float h = sigm(go) * tanhf(c);
      __hip_atomic_store(&h_buf[8 * b + tid], h, __ATOMIC_RELAXED, AGENT);
    }
    __syncthreads();          // compiler drains vmcnt before s_barrier
    if (tid == 0) {
      drain_vmem();
      __hip_atomic_store(&flags_h[b], (unsigned)(t + 1), __ATOMIC_RELAXED, AGENT);
    }
  }

  // ---- publish c ----
  if (tid < 8)
    __hip_atomic_store(&c_buf[8 * b + tid], creg, __ATOMIC_RELAXED, AGENT);
  __syncthreads();
  if (tid == 0) {
    drain_vmem();
    __hip_atomic_store(&flags_m[b], 8193u, __ATOMIC_RELAXED, AGENT);
  }

  if (b != 0) return;

  // ---- final FC chain on block 0 only (~10 MMAC, ~20us) ----
  while (__hip_atomic_load(&flags_m[tid], __ATOMIC_RELAXED, AGENT) < 8193u) {}
  __syncthreads();
  for (int i = tid; i < 2048; i += 256) {
    fcx[i]        = __hip_atomic_load(&h_buf[i], __ATOMIC_RELAXED, AGENT);
    fcx[2048 + i] = __hip_atomic_load(&c_buf[i], __ATOMIC_RELAXED, AGENT);
  }
  __syncthreads();
  // fc1: [2048 x 4096]
  for (int r = tid; r < 2048; r += 256) {
    const float4* wr = (const float4*)(fc1_w + (size_t)r * 4096);
    const float4* xv = (const float4*)fcx;
    float a0 = 0, a1 = 0, a2 = 0, a3 = 0;
    for (int k = 0; k < 1024; ++k) {
      float4 w = wr[k], x = xv[k];
      a0 = fmaf(w.x, x.x, a0); a1 = fmaf(w.y, x.y, a1);
      a2 = fmaf(w.z, x.z, a2); a3 = fmaf(w.w, x.w, a3);
    }
    fy[r] = fmaxf((a0 + a1) + (a2 + a3) + fc1_b[r], 0.f);
  }
  __syncthreads();
  // fc2: [512 x 2048] reads fy -> fcx[0..512)
  for (int r = tid; r < 512; r += 256) {
    const float4* wr = (const float4*)(fc2_w + (size_t)r * 2048);
    const float4* xv = (const float4*)fy;
    float a0 = 0, a1 = 0, a2 = 0, a3 = 0;
    for (int k = 0; k < 512; ++k) {
      float4 w = wr[k], x = xv[k];
      a0 = fmaf(w.x, x.x, a0); a1 = fmaf(w.y, x.y, a1);
      a2 = fmaf(w.z, x.z, a2); a3 = fmaf(w.w, x.w, a3);
    }
    fcx[r] = fmaxf((a0 + a1) + (a2 + a3) + fc2_b[r], 0.f);
  }
  __syncthreads();
  // fc3: [1024 x 512] reads fcx[0..512) -> fy[0..1024)
  for (int r = tid; r < 1024; r += 256) {
    const float4* wr = (const float4*)(fc3_w + (size_t)r * 512);
    const float4* xv = (const float4*)fcx;
    float a0 = 0, a1 = 0, a2 = 0, a3 = 0;
    for (int k = 0; k < 128; ++k) {
      float4 w = wr[k], x = xv[k];
      a0 = fmaf(w.x, x.x, a0); a1 = fmaf(w.y, x.y, a1);
      a2 = fmaf(w.z, x.z, a2); a3 = fmaf(w.w, x.w, a3);
    }
    fy[r] = fmaxf((a0 + a1) + (a2 + a3) + fc3_b[r], 0.f);
  }
  __syncthreads();
  // fc4: [5 x 1024]
  if (tid < 5) {
    const float4* wr = (const float4*)(fc4_w + (size_t)tid * 1024);
    const float4* xv = (const float4*)fy;
    float a0 = 0, a1 = 0, a2 = 0, a3 = 0;
    for (int k = 0; k < 256; ++k) {
      float4 w = wr[k], x = xv[k];
      a0 = fmaf(w.x, x.x, a0); a1 = fmaf(w.y, x.y, a1);
      a2 = fmaf(w.z, x.z, a2); a3 = fmaf(w.w, x.w, a3);
    }
    out[tid] = fmaxf((a0 + a1) + (a2 + a3) + fc4_b[tid], 0.f);
  }
}

extern "C" void kernel_launch(void* const* d_in, const int* in_sizes, int n_in,
                              void* d_out, int out_size, void* d_ws, size_t ws_size,
                              hipStream_t stream)
{
  const int*   tokens = (const int*)  d_in[0];
  const float* embed_w = (const float*)d_in[1];
  const float* wx_w   = (const float*)d_in[2];
  const float* wx_b   = (const float*)d_in[3];
  const float* wh_w   = (const float*)d_in[4];
  const float* wh_b   = (const float*)d_in[5];
  const float* wmx_w  = (const float*)d_in[6];
  const float* wmx_b  = (const float*)d_in[7];
  const float* wmh_w  = (const float*)d_in[8];
  const float* wmh_b  = (const float*)d_in[9];
  const float* fc1_w  = (const float*)d_in[10];
  const float* fc1_b  = (const float*)d_in[11];
  const float* fc2_w  = (const float*)d_in[12];
  const float* fc2_b  = (const float*)d_in[13];
  const float* fc3_w  = (const float*)d_in[14];
  const float* fc3_b  = (const float*)d_in[15];
  const float* fc4_w  = (const float*)d_in[16];
  const float* fc4_b  = (const float*)d_in[17];
  float* out = (float*)d_out;
  float* ws  = (float*)d_ws;

  // zero h_buf/m_buf/c_buf + flags every call (graph-replay safe)
  hipMemsetAsync(d_ws, 0, WS_TOT * sizeof(float), stream);

  // Plain launch: no grid.sync() anywhere; co-residency guaranteed by
  // grid == 256 == #CUs with >= 1 block/CU of resources.
  mlstm_kernel<<<dim3(256), dim3(256), 0, stream>>>(
      tokens, embed_w, wx_w, wx_b, wh_w, wh_b,
      wmx_w, wmx_b, wmh_w, wmh_b,
      fc1_w, fc1_b, fc2_w, fc2_b, fc3_w, fc3_b,
      fc4_w, fc4_b, out, ws);
}

// Round 4
// 92283.789 us; speedup vs baseline: 6.0986x; 1.2213x over previous
//
#include <hip/hip_runtime.h>
#include <math.h>

// mLSTM scan, 8192 serial steps. Weights resident on-chip (wh_w f32 in
// VGPRs/AGPRs: 256/thread; wmh_w bf16-packed in LDS: 32KB/CU), one
// persistent workgroup per CU (256 x 256), per-step cross-CU exchange of
// the 2048-vectors m and h through LLC with flag-per-CU dataflow sync
// (sc1 = LLC coherent point). Final FC chain on block 0 only.
//
// R3 -> R4 (LLC request-pressure reduction on the critical path):
//  1. flag wait: wave 0 only, dwordx4 sc0 sc1 poll (4 flags/lane) +
//     s_sleep(1); waves 1-3 park at __syncthreads. ~16x fewer poll
//     line-requests on the 16 flag cache lines.
//  2. h/m gather: cooperative LDS staging (2x dwordx4 sc0 sc1 per thread,
//     unique lines, 2-deep tail) instead of 4 waves x 32 scalar redundant
//     loads. Stage buffer aliases fcx (block-0 FC scratch) to stay under
//     the 64KB workgroup LDS limit.

#define WS_H   0
#define WS_M   2048
#define WS_C   4096
#define WS_FH  6144
#define WS_FM  6400
#define WS_TOT 6656

#define AGENT __HIP_MEMORY_SCOPE_AGENT

__device__ __forceinline__ void drain_vmem() {
  asm volatile("s_waitcnt vmcnt(0)" ::: "memory");
}

// Coherent 16B load serviced at the LLC (bypasses L1 + non-coherent L2).
__device__ __forceinline__ float4 llc_load4(const float* p) {
  float4 r;
  asm volatile("global_load_dwordx4 %0, %1, off sc0 sc1"
               : "=v"(r) : "v"(p) : "memory");
  return r;
}

__device__ __forceinline__ unsigned umin4(unsigned a, unsigned b,
                                          unsigned c, unsigned d) {
  unsigned x = a < b ? a : b;
  unsigned y = c < d ? c : d;
  return x < y ? x : y;
}

// Wave-0-only wait: lane l covers flags[4l..4l+3]; divergent loop exits
// per-lane, wave exits when all 256 flags >= tgt.
__device__ __forceinline__ void wait_flags(const unsigned* flags,
                                           unsigned tgt, int lane) {
  const unsigned* p = flags + 4 * lane;
  for (;;) {
    uint4 f;
    asm volatile("global_load_dwordx4 %0, %1, off sc0 sc1\n\t"
                 "s_waitcnt vmcnt(0)"
                 : "=v"(f) : "v"(p) : "memory");
    if (umin4(f.x, f.y, f.z, f.w) >= tgt) return;
    __builtin_amdgcn_s_sleep(1);
  }
}

__device__ __forceinline__ float sigm(float x) { return 1.f / (1.f + __expf(-x)); }

__device__ __forceinline__ float wred(float v) {
  v += __shfl_xor(v, 32, 64);
  v += __shfl_xor(v, 16, 64);
  v += __shfl_xor(v, 8, 64);
  v += __shfl_xor(v, 4, 64);
  v += __shfl_xor(v, 2, 64);
  v += __shfl_xor(v, 1, 64);
  return v;
}

__global__ __launch_bounds__(256, 1)
void mlstm_kernel(const int* __restrict__ tokens,
                  const float* __restrict__ embed_w,
                  const float* __restrict__ wx_w,  const float* __restrict__ wx_b,
                  const float* __restrict__ wh_w,  const float* __restrict__ wh_b,
                  const float* __restrict__ wmx_w, const float* __restrict__ wmx_b,
                  const float* __restrict__ wmh_w, const float* __restrict__ wmh_b,
                  const float* __restrict__ fc1_w, const float* __restrict__ fc1_b,
                  const float* __restrict__ fc2_w, const float* __restrict__ fc2_b,
                  const float* __restrict__ fc3_w, const float* __restrict__ fc3_b,
                  const float* __restrict__ fc4_w, const float* __restrict__ fc4_b,
                  float* __restrict__ out, float* __restrict__ ws)
{
  __shared__ unsigned wmh_pk[8][16][64];          // 32KB: wmh rows (8/CU), bf16x2 packed
  __shared__ float gate_lds[4][8];
  __shared__ __align__(16) float fcx[4096];       // gather stage (loop) / FC scratch (tail)
  __shared__ __align__(16) float fy[2048];

  const int tid  = threadIdx.x;
  const int lane = tid & 63;
  const int wv   = tid >> 6;        // wave 0..3 == gate type i,f,g,o
  const int b    = blockIdx.x;      // CU id 0..255

  float* h_buf = ws + WS_H;
  float* m_buf = ws + WS_M;
  float* c_buf = ws + WS_C;
  unsigned* flags_h = (unsigned*)(ws + WS_FH);
  unsigned* flags_m = (unsigned*)(ws + WS_FM);
  float* stage = fcx;               // 2048-float gather buffer (aliased)

  // ---------------- preload weights ----------------
  // wave wv owns gate rows gr = 2048*wv + 8*b + s (s=0..7); lane holds k = lane+64j
  float whR[8][32];
  float wxR[8][2];
  float gBias[8];
  {
    const int gr0 = 2048 * wv + 8 * b;
#pragma unroll
    for (int s = 0; s < 8; ++s) {
      const float* row = wh_w + (size_t)(gr0 + s) * 2048;
#pragma unroll
      for (int j = 0; j < 32; ++j) whR[s][j] = row[lane + 64 * j];
      wxR[s][0] = wx_w[(size_t)(gr0 + s) * 128 + lane];
      wxR[s][1] = wx_w[(size_t)(gr0 + s) * 128 + lane + 64];
      gBias[s] = wh_b[gr0 + s] + wx_b[gr0 + s];
    }
  }
  // wave wv owns hidden units u = 2*wv+rr (local), gu = 8*b+u (global)
  float wmxR[2][2], vB[2], xB[2];
#pragma unroll
  for (int rr = 0; rr < 2; ++rr) {
    const int gu = 8 * b + 2 * wv + rr;
    wmxR[rr][0] = wmx_w[(size_t)gu * 128 + lane];
    wmxR[rr][1] = wmx_w[(size_t)gu * 128 + lane + 64];
    vB[rr] = wmh_b[gu];
    xB[rr] = wmx_b[gu];
  }
  // wmh rows -> LDS as packed bf16 pairs (RNE): lo = w[gu][l+128p], hi = +64.
  for (int idx = tid; idx < 8 * 16 * 64; idx += 256) {
    int u = idx >> 10, p = (idx >> 6) & 15, l = idx & 63;
    float a = wmh_w[(size_t)(8 * b + u) * 2048 + l + 128 * p];
    float c = wmh_w[(size_t)(8 * b + u) * 2048 + l + 128 * p + 64];
    unsigned xa = __float_as_uint(a); xa = (xa + 0x7fffu + ((xa >> 16) & 1u)) >> 16;
    unsigned xc = __float_as_uint(c); xc = (xc + 0x7fffu + ((xc >> 16) & 1u)) >> 16;
    wmh_pk[u][p][l] = xa | (xc << 16);
  }
  __syncthreads();

  float creg = 0.f;
  int tok = tokens[0];
  float e0 = embed_w[tok * 128 + lane];
  float e1 = embed_w[tok * 128 + lane + 64];

  for (int t = 0; t < 8192; ++t) {
    // ---- phase 1: wait h(t-1), gather to LDS, compute m ----
    if (wv == 0) wait_flags(flags_h, (unsigned)t, lane);
    __syncthreads();
    {
      float4 g0 = llc_load4(&h_buf[tid * 8]);
      float4 g1 = llc_load4(&h_buf[tid * 8 + 4]);
      drain_vmem();
      *(float4*)&stage[tid * 8]     = g0;
      *(float4*)&stage[tid * 8 + 4] = g1;
    }
    __syncthreads();
    float hloc[32];
#pragma unroll
    for (int j = 0; j < 32; ++j) hloc[j] = stage[lane + 64 * j];
#pragma unroll
    for (int rr = 0; rr < 2; ++rr) {
      const int u = 2 * wv + rr;
      float acc = 0.f;
#pragma unroll
      for (int p = 0; p < 16; ++p) {
        unsigned pk = wmh_pk[u][p][lane];
        acc = fmaf(__uint_as_float(pk << 16),         hloc[2 * p],     acc);
        acc = fmaf(__uint_as_float(pk & 0xffff0000u), hloc[2 * p + 1], acc);
      }
      float ax = fmaf(wmxR[rr][0], e0, wmxR[rr][1] * e1);
      acc = wred(acc);
      ax  = wred(ax);
      if (lane == 0) {
        float m = (ax + xB[rr]) * (acc + vB[rr]);   // m = xm * (wmh@h + b)
        __hip_atomic_store(&m_buf[8 * b + u], m, __ATOMIC_RELAXED, AGENT);
      }
    }
    __syncthreads();          // all waves' vmcnt drained before barrier
    if (tid == 0) {
      drain_vmem();
      __hip_atomic_store(&flags_m[b], (unsigned)(t + 1), __ATOMIC_RELAXED, AGENT);
    }

    // ---- phase 2: wait all m, gather to LDS, compute gates/h ----
    if (wv == 0) wait_flags(flags_m, (unsigned)(t + 1), lane);
    __syncthreads();
    {
      float4 g0 = llc_load4(&m_buf[tid * 8]);
      float4 g1 = llc_load4(&m_buf[tid * 8 + 4]);
      drain_vmem();
      *(float4*)&stage[tid * 8]     = g0;
      *(float4*)&stage[tid * 8 + 4] = g1;
    }
    __syncthreads();
    float mloc[32];
#pragma unroll
    for (int j = 0; j < 32; ++j) mloc[j] = stage[lane + 64 * j];
    float ga[8];
#pragma unroll
    for (int s = 0; s < 8; ++s) {
      float acc = fmaf(wxR[s][0], e0, wxR[s][1] * e1);   // x_gates folded in
#pragma unroll
      for (int j = 0; j < 32; ++j) acc = fmaf(whR[s][j], mloc[j], acc);
      ga[s] = acc;
    }
    // prefetch next token + embedding (hides under reduce/exchange)
    if (t + 1 < 8192) {
      tok = tokens[t + 1];
      e0 = embed_w[tok * 128 + lane];
      e1 = embed_w[tok * 128 + lane + 64];
    }
#pragma unroll
    for (int s = 0; s < 8; ++s) {
      float r = wred(ga[s]);
      if (lane == 0) gate_lds[wv][s] = r + gBias[s];
    }
    __syncthreads();
    if (tid < 8) {
      float gi = gate_lds[0][tid], gf = gate_lds[1][tid];
      float gg = gate_lds[2][tid], go = gate_lds[3][tid];
      float c = sigm(gf) * creg + sigm(gi) * tanhf(gg);
      creg = c;
      float h = sigm(go) * tanhf(c);
      __hip_atomic_store(&h_buf[8 * b + tid], h, __ATOMIC_RELAXED, AGENT);
    }
    __syncthreads();          // all waves' vmcnt drained before barrier
    if (tid == 0) {
      drain_vmem();
      __hip_atomic_store(&flags_h[b], (unsigned)(t + 1), __ATOMIC_RELAXED, AGENT);
    }
  }

  // ---- publish c ----
  if (tid < 8)
    __hip_atomic_store(&c_buf[8 * b + tid], creg, __ATOMIC_RELAXED, AGENT);
  __syncthreads();
  if (tid == 0) {
    drain_vmem();
    __hip_atomic_store(&flags_m[b], 8193u, __ATOMIC_RELAXED, AGENT);
  }

  if (b != 0) return;

  // ---- final FC chain on block 0 only (~10 MMAC, ~20us) ----
  while (__hip_atomic_load(&flags_m[tid], __ATOMIC_RELAXED, AGENT) < 8193u) {}
  __syncthreads();
  for (int i = tid; i < 2048; i += 256) {
    fcx[i]        = __hip_atomic_load(&h_buf[i], __ATOMIC_RELAXED, AGENT);
    fcx[2048 + i] = __hip_atomic_load(&c_buf[i], __ATOMIC_RELAXED, AGENT);
  }
  __syncthreads();
  // fc1: [2048 x 4096]
  for (int r = tid; r < 2048; r += 256) {
    const float4* wr = (const float4*)(fc1_w + (size_t)r * 4096);
    const float4* xv = (const float4*)fcx;
    float a0 = 0, a1 = 0, a2 = 0, a3 = 0;
    for (int k = 0; k < 1024; ++k) {
      float4 w = wr[k], x = xv[k];
      a0 = fmaf(w.x, x.x, a0); a1 = fmaf(w.y, x.y, a1);
      a2 = fmaf(w.z, x.z, a2); a3 = fmaf(w.w, x.w, a3);
    }
    fy[r] = fmaxf((a0 + a1) + (a2 + a3) + fc1_b[r], 0.f);
  }
  __syncthreads();
  // fc2: [512 x 2048] reads fy -> fcx[0..512)
  for (int r = tid; r < 512; r += 256) {
    const float4* wr = (const float4*)(fc2_w + (size_t)r * 2048);
    const float4* xv = (const float4*)fy;
    float a0 = 0, a1 = 0, a2 = 0, a3 = 0;
    for (int k = 0; k < 512; ++k) {
      float4 w = wr[k], x = xv[k];
      a0 = fmaf(w.x, x.x, a0); a1 = fmaf(w.y, x.y, a1);
      a2 = fmaf(w.z, x.z, a2); a3 = fmaf(w.w, x.w, a3);
    }
    fcx[r] = fmaxf((a0 + a1) + (a2 + a3) + fc2_b[r], 0.f);
  }
  __syncthreads();
  // fc3: [1024 x 512] reads fcx[0..512) -> fy[0..1024)
  for (int r = tid; r < 1024; r += 256) {
    const float4* wr = (const float4*)(fc3_w + (size_t)r * 512);
    const float4* xv = (const float4*)fcx;
    float a0 = 0, a1 = 0, a2 = 0, a3 = 0;
    for (int k = 0; k < 128; ++k) {
      float4 w = wr[k], x = xv[k];
      a0 = fmaf(w.x, x.x, a0); a1 = fmaf(w.y, x.y, a1);
      a2 = fmaf(w.z, x.z, a2); a3 = fmaf(w.w, x.w, a3);
    }
    fy[r] = fmaxf((a0 + a1) + (a2 + a3) + fc3_b[r], 0.f);
  }
  __syncthreads();
  // fc4: [5 x 1024]
  if (tid < 5) {
    const float4* wr = (const float4*)(fc4_w + (size_t)tid * 1024);
    const float4* xv = (const float4*)fy;
    float a0 = 0, a1 = 0, a2 = 0, a3 = 0;
    for (int k = 0; k < 256; ++k) {
      float4 w = wr[k], x = xv[k];
      a0 = fmaf(w.x, x.x, a0); a1 = fmaf(w.y, x.y, a1);
      a2 = fmaf(w.z, x.z, a2); a3 = fmaf(w.w, x.w, a3);
    }
    out[tid] = fmaxf((a0 + a1) + (a2 + a3) + fc4_b[tid], 0.f);
  }
}

extern "C" void kernel_launch(void* const* d_in, const int* in_sizes, int n_in,
                              void* d_out, int out_size, void* d_ws, size_t ws_size,
                              hipStream_t stream)
{
  const int*   tokens = (const int*)  d_in[0];
  const float* embed_w = (const float*)d_in[1];
  const float* wx_w   = (const float*)d_in[2];
  const float* wx_b   = (const float*)d_in[3];
  const float* wh_w   = (const float*)d_in[4];
  const float* wh_b   = (const float*)d_in[5];
  const float* wmx_w  = (const float*)d_in[6];
  const float* wmx_b  = (const float*)d_in[7];
  const float* wmh_w  = (const float*)d_in[8];
  const float* wmh_b  = (const float*)d_in[9];
  const float* fc1_w  = (const float*)d_in[10];
  const float* fc1_b  = (const float*)d_in[11];
  const float* fc2_w  = (const float*)d_in[12];
  const float* fc2_b  = (const float*)d_in[13];
  const float* fc3_w  = (const float*)d_in[14];
  const float* fc3_b  = (const float*)d_in[15];
  const float* fc4_w  = (const float*)d_in[16];
  const float* fc4_b  = (const float*)d_in[17];
  float* out = (float*)d_out;
  float* ws  = (float*)d_ws;

  // zero h_buf/m_buf/c_buf + flags every call (graph-replay safe)
  hipMemsetAsync(d_ws, 0, WS_TOT * sizeof(float), stream);

  // Plain launch: no grid.sync(); co-residency guaranteed by grid == 256 ==
  // #CUs with >= 1 block/CU of resources.
  mlstm_kernel<<<dim3(256), dim3(256), 0, stream>>>(
      tokens, embed_w, wx_w, wx_b, wh_w, wh_b,
      wmx_w, wmx_b, wmh_w, wmh_b,
      fc1_w, fc1_b, fc2_w, fc2_b, fc3_w, fc3_b,
      fc4_w, fc4_b, out, ws);
}

// Round 5
// 86276.672 us; speedup vs baseline: 6.5232x; 1.0696x over previous
//
#include <hip/hip_runtime.h>
#include <math.h>

// mLSTM scan, 8192 serial steps. Weights resident on-chip (wh_w f32 in
// regs: 256/thread; wmh_w bf16-packed in LDS: 32KB/CU), one persistent
// workgroup per CU (256 x 256), per-step cross-CU exchange of the
// 2048-vectors m and h through the LLC. Final FC chain on block 0 only.
//
// R4 -> R5: flagless exchange via self-validating tagged pairs.
// Each exchanged scalar is an 8B (value, step_tag) pair stored with one
// atomic global_store_dwordx2 sc0 sc1 (fire-and-forget). Consumers poll
// the data directly: thread i polls producer-CU i's 64B pair block
// (4 x dwordx4 sc0 sc1) until all 8 tags match the step, then stages the
// values to LDS. Removes per-phase: producer vmcnt-ack RT, flag-store RT,
// flag-poll->gather serialization; barriers 8 -> 4 per step.
// Overwrite safety (single-buffered slots) follows the same induction as
// the flag protocol: a producer can only advance past step t after reading
// all of m(t), which exists only after every CU fully consumed h(t).

#define WS_HP   0          // h pairs: 2048 x (val,tag) = 4096 words
#define WS_MP   4096       // m pairs: 4096 words
#define WS_CP   8192       // c pairs: 4096 words
#define WS_TOT  12288      // words

typedef unsigned u32x4 __attribute__((ext_vector_type(4)));
typedef unsigned u32x2 __attribute__((ext_vector_type(2)));

__device__ __forceinline__ float sigm(float x) { return 1.f / (1.f + __expf(-x)); }

__device__ __forceinline__ float wred(float v) {
  v += __shfl_xor(v, 32, 64);
  v += __shfl_xor(v, 16, 64);
  v += __shfl_xor(v, 8, 64);
  v += __shfl_xor(v, 4, 64);
  v += __shfl_xor(v, 2, 64);
  v += __shfl_xor(v, 1, 64);
  return v;
}

// Store one (value, tag) pair as a single atomic 8B write-through to LLC.
__device__ __forceinline__ void store_pair(unsigned* p, float v, unsigned tag) {
  u32x2 q; q.x = __float_as_uint(v); q.y = tag;
  asm volatile("global_store_dwordx2 %0, %1, off sc0 sc1"
               :: "v"(p), "v"(q) : "memory");
}

// Load 8 pairs (64B) from LLC; returns true when all 8 tags == expect.
// Values are delivered as two float4s. The s_waitcnt is inside the asm and
// the value uses are data-dependent on the asm outputs, so no reordering
// hazard (rule: keep waitcnt + consumed regs in one asm block).
__device__ __forceinline__ bool poll8(const unsigned* p, unsigned expect,
                                      float4* v0, float4* v1) {
  u32x4 a, b, c, d;
  asm volatile(
      "global_load_dwordx4 %0, %4, off sc0 sc1\n\t"
      "global_load_dwordx4 %1, %4, off offset:16 sc0 sc1\n\t"
      "global_load_dwordx4 %2, %4, off offset:32 sc0 sc1\n\t"
      "global_load_dwordx4 %3, %4, off offset:48 sc0 sc1\n\t"
      "s_waitcnt vmcnt(0)"
      : "=&v"(a), "=&v"(b), "=&v"(c), "=&v"(d)
      : "v"(p)
      : "memory");
  bool ok = (a.y == expect) & (a.w == expect) & (b.y == expect) & (b.w == expect)
          & (c.y == expect) & (c.w == expect) & (d.y == expect) & (d.w == expect);
  v0->x = __uint_as_float(a.x); v0->y = __uint_as_float(a.z);
  v0->z = __uint_as_float(b.x); v0->w = __uint_as_float(b.z);
  v1->x = __uint_as_float(c.x); v1->y = __uint_as_float(c.z);
  v1->z = __uint_as_float(d.x); v1->w = __uint_as_float(d.z);
  return ok;
}

// Scalar pair poll (FC tail only).
__device__ __forceinline__ float poll1(const unsigned* p, unsigned expect) {
  for (;;) {
    u32x2 q;
    asm volatile("global_load_dwordx2 %0, %1, off sc0 sc1\n\t"
                 "s_waitcnt vmcnt(0)"
                 : "=&v"(q) : "v"(p) : "memory");
    if (q.y == expect) return __uint_as_float(q.x);
    __builtin_amdgcn_s_sleep(1);
  }
}

__global__ __launch_bounds__(256, 1)
void mlstm_kernel(const int* __restrict__ tokens,
                  const float* __restrict__ embed_w,
                  const float* __restrict__ wx_w,  const float* __restrict__ wx_b,
                  const float* __restrict__ wh_w,  const float* __restrict__ wh_b,
                  const float* __restrict__ wmx_w, const float* __restrict__ wmx_b,
                  const float* __restrict__ wmh_w, const float* __restrict__ wmh_b,
                  const float* __restrict__ fc1_w, const float* __restrict__ fc1_b,
                  const float* __restrict__ fc2_w, const float* __restrict__ fc2_b,
                  const float* __restrict__ fc3_w, const float* __restrict__ fc3_b,
                  const float* __restrict__ fc4_w, const float* __restrict__ fc4_b,
                  float* __restrict__ out, float* __restrict__ ws)
{
  __shared__ unsigned wmh_pk[8][16][64];          // 32KB: wmh rows, bf16x2 packed
  __shared__ float gate_lds[4][8];
  __shared__ __align__(16) float fcx[4096];       // gather stage (loop) / FC scratch
  __shared__ __align__(16) float fy[2048];

  const int tid  = threadIdx.x;
  const int lane = tid & 63;
  const int wv   = tid >> 6;        // wave 0..3 == gate type i,f,g,o
  const int b    = blockIdx.x;      // CU id 0..255

  unsigned* h_pairs = (unsigned*)ws + WS_HP;
  unsigned* m_pairs = (unsigned*)ws + WS_MP;
  unsigned* c_pairs = (unsigned*)ws + WS_CP;
  float* stage = fcx;               // 2048-float gather buffer (aliased)

  // ---------------- preload weights ----------------
  float whR[8][32];
  float wxR[8][2];
  float gBias[8];
  {
    const int gr0 = 2048 * wv + 8 * b;
#pragma unroll
    for (int s = 0; s < 8; ++s) {
      const float* row = wh_w + (size_t)(gr0 + s) * 2048;
#pragma unroll
      for (int j = 0; j < 32; ++j) whR[s][j] = row[lane + 64 * j];
      wxR[s][0] = wx_w[(size_t)(gr0 + s) * 128 + lane];
      wxR[s][1] = wx_w[(size_t)(gr0 + s) * 128 + lane + 64];
      gBias[s] = wh_b[gr0 + s] + wx_b[gr0 + s];
    }
  }
  float wmxR[2][2], vB[2], xB[2];
#pragma unroll
  for (int rr = 0; rr < 2; ++rr) {
    const int gu = 8 * b + 2 * wv + rr;
    wmxR[rr][0] = wmx_w[(size_t)gu * 128 + lane];
    wmxR[rr][1] = wmx_w[(size_t)gu * 128 + lane + 64];
    vB[rr] = wmh_b[gu];
    xB[rr] = wmx_b[gu];
  }
  // wmh rows -> LDS as packed bf16 pairs (RNE).
  for (int idx = tid; idx < 8 * 16 * 64; idx += 256) {
    int u = idx >> 10, p = (idx >> 6) & 15, l = idx & 63;
    float a = wmh_w[(size_t)(8 * b + u) * 2048 + l + 128 * p];
    float c = wmh_w[(size_t)(8 * b + u) * 2048 + l + 128 * p + 64];
    unsigned xa = __float_as_uint(a); xa = (xa + 0x7fffu + ((xa >> 16) & 1u)) >> 16;
    unsigned xc = __float_as_uint(c); xc = (xc + 0x7fffu + ((xc >> 16) & 1u)) >> 16;
    wmh_pk[u][p][l] = xa | (xc << 16);
  }
  __syncthreads();

  float creg = 0.f;
  int tok = tokens[0];
  float e0 = embed_w[tok * 128 + lane];
  float e1 = embed_w[tok * 128 + lane + 64];

  for (int t = 0; t < 8192; ++t) {
    // ---- phase 1: poll h(t) pairs (tag == t; t=0 served by memset zeros) ----
    {
      float4 v0, v1;
      while (!poll8(h_pairs + 16 * tid, (unsigned)t, &v0, &v1))
        __builtin_amdgcn_s_sleep(1);
      *(float4*)&stage[tid * 8]     = v0;
      *(float4*)&stage[tid * 8 + 4] = v1;
    }
    __syncthreads();                      // stage complete
    float hloc[32];
#pragma unroll
    for (int j = 0; j < 32; ++j) hloc[j] = stage[lane + 64 * j];
#pragma unroll
    for (int rr = 0; rr < 2; ++rr) {
      const int u = 2 * wv + rr;
      float acc = 0.f;
#pragma unroll
      for (int p = 0; p < 16; ++p) {
        unsigned pk = wmh_pk[u][p][lane];
        acc = fmaf(__uint_as_float(pk << 16),         hloc[2 * p],     acc);
        acc = fmaf(__uint_as_float(pk & 0xffff0000u), hloc[2 * p + 1], acc);
      }
      float ax = fmaf(wmxR[rr][0], e0, wmxR[rr][1] * e1);
      acc = wred(acc);
      ax  = wred(ax);
      if (lane == 0) {
        float m = (ax + xB[rr]) * (acc + vB[rr]);   // m = xm * (wmh@h + b)
        store_pair(m_pairs + 2 * (8 * b + u), m, (unsigned)(t + 1));
      }
    }
    __syncthreads();   // all stage reads done before phase-2 poll overwrites

    // ---- phase 2: poll m(t) pairs (tag == t+1) ----
    {
      float4 v0, v1;
      while (!poll8(m_pairs + 16 * tid, (unsigned)(t + 1), &v0, &v1))
        __builtin_amdgcn_s_sleep(1);
      *(float4*)&stage[tid * 8]     = v0;
      *(float4*)&stage[tid * 8 + 4] = v1;
    }
    __syncthreads();
    float mloc[32];
#pragma unroll
    for (int j = 0; j < 32; ++j) mloc[j] = stage[lane + 64 * j];
    float ga[8];
#pragma unroll
    for (int s = 0; s < 8; ++s) {
      float acc = fmaf(wxR[s][0], e0, wxR[s][1] * e1);   // x_gates folded in
#pragma unroll
      for (int j = 0; j < 32; ++j) acc = fmaf(whR[s][j], mloc[j], acc);
      ga[s] = acc;
    }
    // prefetch next token + embedding (hides under reduce/exchange)
    if (t + 1 < 8192) {
      tok = tokens[t + 1];
      e0 = embed_w[tok * 128 + lane];
      e1 = embed_w[tok * 128 + lane + 64];
    }
#pragma unroll
    for (int s = 0; s < 8; ++s) {
      float r = wred(ga[s]);
      if (lane == 0) gate_lds[wv][s] = r + gBias[s];
    }
    __syncthreads();   // gate_lds complete; stage dead -> next poll may overwrite
    if (tid < 8) {
      float gi = gate_lds[0][tid], gf = gate_lds[1][tid];
      float gg = gate_lds[2][tid], go = gate_lds[3][tid];
      float c = sigm(gf) * creg + sigm(gi) * tanhf(gg);
      creg = c;
      float h = sigm(go) * tanhf(c);
      store_pair(h_pairs + 2 * (8 * b + tid), h, (unsigned)(t + 1));
    }
  }

  // ---- publish c (tag 8193 distinguishes from memset 0) ----
  if (tid < 8)
    store_pair(c_pairs + 2 * (8 * b + tid), creg, 8193u);

  if (b != 0) return;

  // ---- final FC chain on block 0 only (~10 MMAC) ----
  // h(8192) pairs carry tag 8192; c pairs tag 8193.
  for (int i = tid; i < 2048; i += 256) {
    fcx[i]        = poll1(h_pairs + 2 * i, 8192u);
    fcx[2048 + i] = poll1(c_pairs + 2 * i, 8193u);
  }
  __syncthreads();
  // fc1: [2048 x 4096]
  for (int r = tid; r < 2048; r += 256) {
    const float4* wr = (const float4*)(fc1_w + (size_t)r * 4096);
    const float4* xv = (const float4*)fcx;
    float a0 = 0, a1 = 0, a2 = 0, a3 = 0;
    for (int k = 0; k < 1024; ++k) {
      float4 w = wr[k], x = xv[k];
      a0 = fmaf(w.x, x.x, a0); a1 = fmaf(w.y, x.y, a1);
      a2 = fmaf(w.z, x.z, a2); a3 = fmaf(w.w, x.w, a3);
    }
    fy[r] = fmaxf((a0 + a1) + (a2 + a3) + fc1_b[r], 0.f);
  }
  __syncthreads();
  // fc2: [512 x 2048]
  for (int r = tid; r < 512; r += 256) {
    const float4* wr = (const float4*)(fc2_w + (size_t)r * 2048);
    const float4* xv = (const float4*)fy;
    float a0 = 0, a1 = 0, a2 = 0, a3 = 0;
    for (int k = 0; k < 512; ++k) {
      float4 w = wr[k], x = xv[k];
      a0 = fmaf(w.x, x.x, a0); a1 = fmaf(w.y, x.y, a1);
      a2 = fmaf(w.z, x.z, a2); a3 = fmaf(w.w, x.w, a3);
    }
    fcx[r] = fmaxf((a0 + a1) + (a2 + a3) + fc2_b[r], 0.f);
  }
  __syncthreads();
  // fc3: [1024 x 512]
  for (int r = tid; r < 1024; r += 256) {
    const float4* wr = (const float4*)(fc3_w + (size_t)r * 512);
    const float4* xv = (const float4*)fcx;
    float a0 = 0, a1 = 0, a2 = 0, a3 = 0;
    for (int k = 0; k < 128; ++k) {
      float4 w = wr[k], x = xv[k];
      a0 = fmaf(w.x, x.x, a0); a1 = fmaf(w.y, x.y, a1);
      a2 = fmaf(w.z, x.z, a2); a3 = fmaf(w.w, x.w, a3);
    }
    fy[r] = fmaxf((a0 + a1) + (a2 + a3) + fc3_b[r], 0.f);
  }
  __syncthreads();
  // fc4: [5 x 1024]
  if (tid < 5) {
    const float4* wr = (const float4*)(fc4_w + (size_t)tid * 1024);
    const float4* xv = (const float4*)fy;
    float a0 = 0, a1 = 0, a2 = 0, a3 = 0;
    for (int k = 0; k < 256; ++k) {
      float4 w = wr[k], x = xv[k];
      a0 = fmaf(w.x, x.x, a0); a1 = fmaf(w.y, x.y, a1);
      a2 = fmaf(w.z, x.z, a2); a3 = fmaf(w.w, x.w, a3);
    }
    out[tid] = fmaxf((a0 + a1) + (a2 + a3) + fc4_b[tid], 0.f);
  }
}

extern "C" void kernel_launch(void* const* d_in, const int* in_sizes, int n_in,
                              void* d_out, int out_size, void* d_ws, size_t ws_size,
                              hipStream_t stream)
{
  const int*   tokens = (const int*)  d_in[0];
  const float* embed_w = (const float*)d_in[1];
  const float* wx_w   = (const float*)d_in[2];
  const float* wx_b   = (const float*)d_in[3];
  const float* wh_w   = (const float*)d_in[4];
  const float* wh_b   = (const float*)d_in[5];
  const float* wmx_w  = (const float*)d_in[6];
  const float* wmx_b  = (const float*)d_in[7];
  const float* wmh_w  = (const float*)d_in[8];
  const float* wmh_b  = (const float*)d_in[9];
  const float* fc1_w  = (const float*)d_in[10];
  const float* fc1_b  = (const float*)d_in[11];
  const float* fc2_w  = (const float*)d_in[12];
  const float* fc2_b  = (const float*)d_in[13];
  const float* fc3_w  = (const float*)d_in[14];
  const float* fc3_b  = (const float*)d_in[15];
  const float* fc4_w  = (const float*)d_in[16];
  const float* fc4_b  = (const float*)d_in[17];
  float* out = (float*)d_out;
  float* ws  = (float*)d_ws;

  // zero all pair tags every call (graph-replay safe; h tags 0 == h(0)=0)
  hipMemsetAsync(d_ws, 0, WS_TOT * sizeof(float), stream);

  mlstm_kernel<<<dim3(256), dim3(256), 0, stream>>>(
      tokens, embed_w, wx_w, wx_b, wh_w, wh_b,
      wmx_w, wmx_b, wmh_w, wmh_b,
      fc1_w, fc1_b, fc2_w, fc2_b, fc3_w, fc3_b,
      fc4_w, fc4_b, out, ws);
}